// Round 5
// baseline (123.928 us; speedup 1.0000x reference)
//
#include <hip/hip_runtime.h>
#include <stdint.h>

#define IN_F 4096
#define OUT_F 4096
#define M_ROWS 4096   // B*S
#define BM 256
#define BN 128
#define BK 32
#define LDA_BYTES (BM * BK * 2)          // 16 KiB
#define LDB_BYTES (BN * BK * 2)          // 8 KiB
#define BUF_BYTES (LDA_BYTES + LDB_BYTES) // 24 KiB per tile-buffer

typedef __attribute__((ext_vector_type(8))) short bf16x8;
typedef __attribute__((ext_vector_type(4))) float f32x4;
typedef __attribute__((ext_vector_type(4))) float f4;
typedef __attribute__((ext_vector_type(8))) unsigned short u16x8;

__device__ __forceinline__ unsigned short f32_to_bf16_rne(float f) {
    uint32_t u = __float_as_uint(f);
    u += 0x7FFFu + ((u >> 16) & 1u);
    return (unsigned short)(u >> 16);
}

// ---- merged prepass: x fp32->bf16 (blocks [0,8192)), W expand (blocks [8192,16384)) ----
__global__ __launch_bounds__(256) void prep_kernel(const float* __restrict__ x,
                                                   const float* __restrict__ wsrc,
                                                   unsigned short* __restrict__ xb,
                                                   unsigned short* __restrict__ wb) {
    int b = blockIdx.x;
    if (b < 8192) {
        size_t g = (size_t)b * 256 + threadIdx.x;   // one per 8 elems
        const f4* xp = (const f4*)x + g * 2;
        f4 a = xp[0], c = xp[1];
        u16x8 r;
        r[0] = f32_to_bf16_rne(a[0]); r[1] = f32_to_bf16_rne(a[1]);
        r[2] = f32_to_bf16_rne(a[2]); r[3] = f32_to_bf16_rne(a[3]);
        r[4] = f32_to_bf16_rne(c[0]); r[5] = f32_to_bf16_rne(c[1]);
        r[6] = f32_to_bf16_rne(c[2]); r[7] = f32_to_bf16_rne(c[3]);
        *((u16x8*)xb + g) = r;
    } else {
        size_t g = (size_t)(b - 8192) * 256 + threadIdx.x;
        int o  = (int)(g >> 9);
        int i0 = ((int)g & 511) << 3;
        int bs = (o >> 7) << 7;            // GEMM never reads i < 128-aligned block start
        if (i0 >= bs) {
            int off = o * IN_F - ((o * (o - 1)) >> 1);
            u16x8 r;
#pragma unroll
            for (int j = 0; j < 8; ++j) {
                int i = i0 + j;
                float v = (i >= o) ? wsrc[off + (i - o)] : 0.0f;
                r[j] = f32_to_bf16_rne(v);
            }
            *((u16x8*)wb + g) = r;
        }
    }
}

// ---- LDS layout (pair-line XOR swizzle, conflict-free for frag reads) ----
// row is 32 bf16 = 64B = 4 slots of 16B. Two rows share a 128B line.
// byte(row, slot) = (row>>1)*128 + ((((row&1)<<2) + slot) ^ ((row>>1)&7)) * 16
__device__ __forceinline__ const bf16x8* lds_frag(const char* buf, int row, int khalf) {
    const int line = row >> 1;
    const int pos  = ((((row & 1) << 2) + khalf) ^ (line & 7));
    return (const bf16x8*)(buf + line * 128 + pos * 16);
}

// stage 16 rows (1 KiB) via one global_load_lds; dest linear, source pre-swizzled
__device__ __forceinline__ void stage16(const unsigned short* __restrict__ G,
                                        char* lds_dst, int gr0, int k0, int lane) {
    const int pos  = (lane & 7) ^ (lane >> 3);
    const int row  = ((lane >> 3) << 1) + (pos >> 2);
    const int slot = pos & 3;
    const unsigned short* src = G + (size_t)(gr0 + row) * IN_F + k0 + slot * 8;
    __builtin_amdgcn_global_load_lds(
        (const __attribute__((address_space(1))) void*)src,
        (__attribute__((address_space(3))) void*)lds_dst, 16, 0, 0);
}

// one K32-tile: A 256x32 (4 chunks/wave) + B 128x32 (2 chunks/wave) = 6 loads/thread
__device__ __forceinline__ void stage_tile(const unsigned short* __restrict__ A,
                                           const unsigned short* __restrict__ W,
                                           char* buf, int m_base, int n_base, int k0,
                                           int wid, int lane) {
    char* bufA = buf;
    char* bufB = buf + LDA_BYTES;
#pragma unroll
    for (int q = 0; q < 4; ++q) {
        const int r0 = q * 64 + wid * 16;
        stage16(A, bufA + r0 * 64, m_base + r0, k0, lane);
    }
#pragma unroll
    for (int q = 0; q < 2; ++q) {
        const int r0 = q * 64 + wid * 16;
        stage16(W, bufB + r0 * 64, n_base + r0, k0, lane);
    }
}

// ---- main GEMM: C[m][n] = sum_{k>=n_base} A[m][k]*W[n][k] + bias[n] ----
// 256 threads = 4 waves, wave grid 2Mx2N, 128x64 output per wave, 2 blocks/CU.
__global__ __launch_bounds__(256, 2) void tri_gemm_kernel(const unsigned short* __restrict__ A,
                                                          const unsigned short* __restrict__ W,
                                                          const float* __restrict__ bias,
                                                          float* __restrict__ C) {
    __shared__ __align__(16) char smem[3 * BUF_BYTES];   // 72 KiB -> 2 blocks/CU

    const int u = blockIdx.x;
    const int v = u >> 4;
    const int tile_n = (v < 16) ? v : 47 - v;   // LPT pairing: CU gets (t, 31-t) -> 66 steps
    const int tile_m = u & 15;
    const int m_base = tile_m * BM;
    const int n_base = tile_n * BN;
    const int nt = (IN_F - n_base) / BK;        // 128 - 4*tile_n, min 4

    const int tid  = threadIdx.x;
    const int wid  = tid >> 6;
    const int lane = tid & 63;
    const int wr = wid >> 1;            // 0..1 (128-row band)
    const int wc = wid & 1;             // 0..1 (64-col band)
    const int frow  = lane & 15;
    const int khalf = lane >> 4;        // 0..3 (k 16B slot)

    char* b0 = smem;
    char* b1 = smem + BUF_BYTES;
    char* b2 = smem + 2 * BUF_BYTES;

    f32x4 acc[8][4];
#pragma unroll
    for (int i = 0; i < 8; ++i)
#pragma unroll
        for (int j = 0; j < 4; ++j) acc[i][j] = (f32x4){0.f, 0.f, 0.f, 0.f};

    // prologue: tiles 0,1 in flight (6 loads each per thread)
    stage_tile(A, W, b0, m_base, n_base, n_base,      wid, lane);
    stage_tile(A, W, b1, m_base, n_base, n_base + BK, wid, lane);

    for (int t = 0; t < nt; ++t) {
        if (t + 1 < nt) { asm volatile("s_waitcnt vmcnt(6)" ::: "memory"); }
        else            { asm volatile("s_waitcnt vmcnt(0)" ::: "memory"); }
        __builtin_amdgcn_sched_barrier(0);
        __builtin_amdgcn_s_barrier();     // tile t staged; reads of t-1 retired by all waves
        __builtin_amdgcn_sched_barrier(0);

        if (t + 2 < nt)                   // prefetch t+2 into buffer freed by t-1
            stage_tile(A, W, b2, m_base, n_base, n_base + (t + 2) * BK, wid, lane);

        const char* bufA = b0;
        const char* bufB = b0 + LDA_BYTES;
        bf16x8 af[8], bfv[4];
#pragma unroll
        for (int mi = 0; mi < 8; ++mi)
            af[mi] = *lds_frag(bufA, wr * 128 + mi * 16 + frow, khalf);
#pragma unroll
        for (int nj = 0; nj < 4; ++nj)
            bfv[nj] = *lds_frag(bufB, wc * 64 + nj * 16 + frow, khalf);

        __builtin_amdgcn_s_setprio(1);
#pragma unroll
        for (int mi = 0; mi < 8; ++mi)
#pragma unroll
            for (int nj = 0; nj < 4; ++nj)
                acc[mi][nj] = __builtin_amdgcn_mfma_f32_16x16x32_bf16(af[mi], bfv[nj], acc[mi][nj], 0, 0, 0);
        __builtin_amdgcn_s_setprio(0);

        char* tmp = b0; b0 = b1; b1 = b2; b2 = tmp;   // rotate
    }

    // ---- epilogue: D layout col=lane&15, row=(lane>>4)*4+q ----
    const int col0 = n_base + wc * 64;
    const int row0 = m_base + wr * 128;
#pragma unroll
    for (int nj = 0; nj < 4; ++nj) {
        const int col = col0 + nj * 16 + frow;
        const float bv = bias[col];
#pragma unroll
        for (int mi = 0; mi < 8; ++mi) {
            const int rbase = row0 + mi * 16 + khalf * 4;
#pragma unroll
            for (int q = 0; q < 4; ++q) {
                C[(size_t)(rbase + q) * OUT_F + col] = acc[mi][nj][q] + bv;
            }
        }
    }
}

extern "C" void kernel_launch(void* const* d_in, const int* in_sizes, int n_in,
                              void* d_out, int out_size, void* d_ws, size_t ws_size,
                              hipStream_t stream) {
    const float* x    = (const float*)d_in[0];
    const float* w    = (const float*)d_in[1];
    const float* bias = (const float*)d_in[2];
    float* out = (float*)d_out;

    unsigned short* xb = (unsigned short*)d_ws;                  // 32 MiB bf16 x
    unsigned short* wb = xb + (size_t)M_ROWS * IN_F;             // 32 MiB bf16 dense W

    prep_kernel<<<16384, 256, 0, stream>>>(x, w, xb, wb);
    tri_gemm_kernel<<<512, 256, 0, stream>>>(xb, wb, bias, out);
}

// Round 6
// 117.516 us; speedup vs baseline: 1.0546x; 1.0546x over previous
//
#include <hip/hip_runtime.h>
#include <stdint.h>

#define IN_F 4096
#define OUT_F 4096
#define M_ROWS 4096   // B*S
#define BM 256
#define BN 128
#define BK 64
#define LDA_B (BM * BK * 2)        // 32 KiB
#define LDB_B (BN * BK * 2)        // 16 KiB
#define BUF_B (LDA_B + LDB_B)      // 48 KiB

typedef __attribute__((ext_vector_type(8))) short bf16x8;
typedef __attribute__((ext_vector_type(4))) float f32x4;
typedef __attribute__((ext_vector_type(4))) float f4;
typedef __attribute__((ext_vector_type(8))) unsigned short u16x8;

__device__ __forceinline__ unsigned short f32_to_bf16_rne(float f) {
    uint32_t u = __float_as_uint(f);
    u += 0x7FFFu + ((u >> 16) & 1u);
    return (unsigned short)(u >> 16);
}

// ---- merged prepass: x fp32->bf16 (blocks [0,8192)), W expand (blocks [8192,16384)) ----
__global__ __launch_bounds__(256) void prep_kernel(const float* __restrict__ x,
                                                   const float* __restrict__ wsrc,
                                                   unsigned short* __restrict__ xb,
                                                   unsigned short* __restrict__ wb) {
    int b = blockIdx.x;
    if (b < 8192) {
        size_t g = (size_t)b * 256 + threadIdx.x;   // one per 8 elems
        const f4* xp = (const f4*)x + g * 2;
        f4 a = xp[0], c = xp[1];
        u16x8 r;
        r[0] = f32_to_bf16_rne(a[0]); r[1] = f32_to_bf16_rne(a[1]);
        r[2] = f32_to_bf16_rne(a[2]); r[3] = f32_to_bf16_rne(a[3]);
        r[4] = f32_to_bf16_rne(c[0]); r[5] = f32_to_bf16_rne(c[1]);
        r[6] = f32_to_bf16_rne(c[2]); r[7] = f32_to_bf16_rne(c[3]);
        *((u16x8*)xb + g) = r;
    } else {
        size_t g = (size_t)(b - 8192) * 256 + threadIdx.x;
        int o  = (int)(g >> 9);
        int i0 = ((int)g & 511) << 3;
        int bs = (o >> 7) << 7;            // GEMM never reads i < 128-aligned block start
        if (i0 >= bs) {
            int off = o * IN_F - ((o * (o - 1)) >> 1);
            u16x8 r;
#pragma unroll
            for (int j = 0; j < 8; ++j) {
                int i = i0 + j;
                float v = (i >= o) ? wsrc[off + (i - o)] : 0.0f;
                r[j] = f32_to_bf16_rne(v);
            }
            *((u16x8*)wb + g) = r;
        }
    }
}

// ---- stage one 8-row x 128B unit via global_load_lds; dest linear, source pre-swizzled ----
// LDS row layout: [row][8 slots x 16B], byte(row,slot) = row*128 + (slot ^ (row&7))*16
__device__ __forceinline__ void stage16(const unsigned short* __restrict__ G,
                                        char* lds_dst, int gr0, int k0, int lane) {
    const int lrow  = lane >> 3;                 // 0..7
    const int gslot = (lane & 7) ^ lrow;         // pre-swizzled source slot
    const unsigned short* src = G + (size_t)(gr0 + lrow) * IN_F + k0 + gslot * 8;
    __builtin_amdgcn_global_load_lds(
        (const __attribute__((address_space(1))) void*)src,
        (__attribute__((address_space(3))) void*)lds_dst, 16, 0, 0);
}

// piece P0 of a K-tile: A rows {band+0..31 of each 64-band} + ALL of B  (4 loads/thread)
__device__ __forceinline__ void issueP0(const unsigned short* __restrict__ A,
                                        const unsigned short* __restrict__ W,
                                        char* buf, int m_base, int n_base, int k0,
                                        int wid, int lane) {
    char* bufA = buf;
    char* bufB = buf + LDA_B;
#pragma unroll
    for (int q = 0; q < 2; ++q) {
        const int idx = wid * 2 + q;                       // 0..15
        const int ru  = (idx & 3) + ((idx >> 2) << 3);     // {0..3,8..11,16..19,24..27}
        stage16(A, bufA + ru * 1024, m_base + ru * 8, k0, lane);
    }
#pragma unroll
    for (int q = 0; q < 2; ++q) {
        const int bu = wid * 2 + q;                        // 0..15
        stage16(W, bufB + bu * 1024, n_base + bu * 8, k0, lane);
    }
}

// piece P1: A rows {band+32..63 of each 64-band}  (2 loads/thread)
__device__ __forceinline__ void issueP1(const unsigned short* __restrict__ A,
                                        char* buf, int m_base, int k0,
                                        int wid, int lane) {
    char* bufA = buf;
#pragma unroll
    for (int q = 0; q < 2; ++q) {
        const int idx = wid * 2 + q;
        const int ru  = (idx & 3) + ((idx >> 2) << 3) + 4; // {4..7,12..15,20..23,28..31}
        stage16(A, bufA + ru * 1024, m_base + ru * 8, k0, lane);
    }
}

__device__ __forceinline__ const bf16x8* lds_frag(const char* buf, int row, int slot) {
    return (const bf16x8*)(buf + row * 128 + ((slot ^ (row & 7)) * 16));
}

// ---- main GEMM: C[m][n] = sum_{k>=n_base} A[m][k]*W[n][k] + bias[n] ----
// 512 thr = 8 waves (4M x 2N), wave tile 64x64. 2-phase piece-pipelined K loop.
__global__ __launch_bounds__(512, 2) void tri_gemm_kernel(const unsigned short* __restrict__ A,
                                                          const unsigned short* __restrict__ W,
                                                          const float* __restrict__ bias,
                                                          float* __restrict__ C) {
    __shared__ __align__(16) char smem[2 * BUF_B];   // 96 KiB double buffer

    const int u = blockIdx.x;
    const int tile_n = u >> 4;          // blocks in desc-K order -> greedy LPT balance
    const int tile_m = u & 15;
    const int m_base = tile_m * BM;
    const int n_base = tile_n * BN;
    const int nt = (IN_F - n_base) / BK;   // 64 - 2*tile_n, min 2

    const int tid  = threadIdx.x;
    const int wid  = tid >> 6;
    const int lane = tid & 63;
    const int wr = wid >> 1;            // 0..3 (64-row band)
    const int wc = wid & 1;             // 0..1 (64-col band)
    const int frow  = lane & 15;
    const int khalf = lane >> 4;        // 0..3 (k 16B slot within 32-k half)

    f32x4 acc[4][4];
#pragma unroll
    for (int i = 0; i < 4; ++i)
#pragma unroll
        for (int j = 0; j < 4; ++j) acc[i][j] = (f32x4){0.f, 0.f, 0.f, 0.f};

    // prologue: tile 0 pieces into buf0; P0 resident before loop, P1 may fly
    issueP0(A, W, smem, m_base, n_base, n_base, wid, lane);
    issueP1(A, smem, m_base, n_base, wid, lane);
    asm volatile("s_waitcnt vmcnt(2)" ::: "memory");
    __builtin_amdgcn_sched_barrier(0);
    __builtin_amdgcn_s_barrier();
    __builtin_amdgcn_sched_barrier(0);

    for (int t = 0; t < nt; ++t) {
        char* cur = smem + (size_t)(t & 1) * BUF_B;
        char* nxt = smem + (size_t)((t + 1) & 1) * BUF_B;
        const int knext = n_base + (t + 1) * BK;
        const char* bufA = cur;
        const char* bufB = cur + LDA_B;

        // ======== phase 0: mi 0,1 x all nj x both kh (16 MFMA) ========
        {
            bf16x8 af[2][2], bfr[2][4];
#pragma unroll
            for (int kh = 0; kh < 2; ++kh) {
#pragma unroll
                for (int mi = 0; mi < 2; ++mi)
                    af[kh][mi] = *lds_frag(bufA, wr * 64 + mi * 16 + frow, kh * 4 + khalf);
#pragma unroll
                for (int nj = 0; nj < 4; ++nj)
                    bfr[kh][nj] = *lds_frag(bufB, wc * 64 + nj * 16 + frow, kh * 4 + khalf);
            }
            if (t + 1 < nt) {
                issueP0(A, W, nxt, m_base, n_base, knext, wid, lane);
                asm volatile("s_waitcnt vmcnt(4)" ::: "memory");  // retire P1(t); P0(t+1) flies
            } else {
                asm volatile("s_waitcnt vmcnt(0)" ::: "memory");  // tail: need P1(last)
            }
            __builtin_amdgcn_sched_barrier(0);
            __builtin_amdgcn_s_barrier();
            __builtin_amdgcn_sched_barrier(0);
            __builtin_amdgcn_s_setprio(1);
#pragma unroll
            for (int kh = 0; kh < 2; ++kh)
#pragma unroll
                for (int mi = 0; mi < 2; ++mi)
#pragma unroll
                    for (int nj = 0; nj < 4; ++nj)
                        acc[mi][nj] = __builtin_amdgcn_mfma_f32_16x16x32_bf16(af[kh][mi], bfr[kh][nj], acc[mi][nj], 0, 0, 0);
            __builtin_amdgcn_s_setprio(0);
            __builtin_amdgcn_s_barrier();

            // ======== phase 1: mi 2,3 x all nj x both kh (16 MFMA) ========
            bf16x8 ag[2][2];
#pragma unroll
            for (int kh = 0; kh < 2; ++kh)
#pragma unroll
                for (int mi = 0; mi < 2; ++mi)
                    ag[kh][mi] = *lds_frag(bufA, wr * 64 + (mi + 2) * 16 + frow, kh * 4 + khalf);
            if (t + 1 < nt)
                issueP1(A, nxt, m_base, knext, wid, lane);
            asm volatile("s_waitcnt vmcnt(2)" ::: "memory");      // retire P0(t+1); P1(t+1) flies
            __builtin_amdgcn_sched_barrier(0);
            __builtin_amdgcn_s_barrier();
            __builtin_amdgcn_sched_barrier(0);
            __builtin_amdgcn_s_setprio(1);
#pragma unroll
            for (int kh = 0; kh < 2; ++kh)
#pragma unroll
                for (int mi = 0; mi < 2; ++mi)
#pragma unroll
                    for (int nj = 0; nj < 4; ++nj)
                        acc[mi + 2][nj] = __builtin_amdgcn_mfma_f32_16x16x32_bf16(ag[kh][mi], bfr[kh][nj], acc[mi + 2][nj], 0, 0, 0);
            __builtin_amdgcn_s_setprio(0);
            __builtin_amdgcn_s_barrier();
        }
    }

    // ---- epilogue: D layout col=lane&15, row=(lane>>4)*4+q ----
    const int col0 = n_base + wc * 64;
    const int row0 = m_base + wr * 64;
#pragma unroll
    for (int nj = 0; nj < 4; ++nj) {
        const int col = col0 + nj * 16 + frow;
        const float bv = bias[col];
#pragma unroll
        for (int mi = 0; mi < 4; ++mi) {
            const int rbase = row0 + mi * 16 + khalf * 4;
#pragma unroll
            for (int q = 0; q < 4; ++q) {
                C[(size_t)(rbase + q) * OUT_F + col] = acc[mi][nj][q] + bv;
            }
        }
    }
}

extern "C" void kernel_launch(void* const* d_in, const int* in_sizes, int n_in,
                              void* d_out, int out_size, void* d_ws, size_t ws_size,
                              hipStream_t stream) {
    const float* x    = (const float*)d_in[0];
    const float* w    = (const float*)d_in[1];
    const float* bias = (const float*)d_in[2];
    float* out = (float*)d_out;

    unsigned short* xb = (unsigned short*)d_ws;                  // 32 MiB bf16 x
    unsigned short* wb = xb + (size_t)M_ROWS * IN_F;             // 32 MiB bf16 dense W

    prep_kernel<<<16384, 256, 0, stream>>>(x, w, xb, wb);
    tri_gemm_kernel<<<512, 512, 0, stream>>>(xb, wb, bias, out);
}

// Round 7
// 116.744 us; speedup vs baseline: 1.0615x; 1.0066x over previous
//
#include <hip/hip_runtime.h>
#include <stdint.h>

#define IN_F 4096
#define OUT_F 4096
#define M_ROWS 4096   // B*S
#define BM 256
#define BN 128
#define BK 64
#define LDA_B (BM * BK * 2)        // 32 KiB
#define LDB_B (BN * BK * 2)        // 16 KiB
#define BUF_B (LDA_B + LDB_B)      // 48 KiB

typedef __attribute__((ext_vector_type(8))) short bf16x8;
typedef __attribute__((ext_vector_type(4))) float f32x4;
typedef __attribute__((ext_vector_type(4))) float f4;
typedef __attribute__((ext_vector_type(8))) unsigned short u16x8;

__device__ __forceinline__ unsigned short f32_to_bf16_rne(float f) {
    uint32_t u = __float_as_uint(f);
    u += 0x7FFFu + ((u >> 16) & 1u);
    return (unsigned short)(u >> 16);
}

// ---- merged prepass: x fp32->bf16 (blocks [0,8192)), W expand (blocks [8192,16384)) ----
__global__ __launch_bounds__(256) void prep_kernel(const float* __restrict__ x,
                                                   const float* __restrict__ wsrc,
                                                   unsigned short* __restrict__ xb,
                                                   unsigned short* __restrict__ wb) {
    int b = blockIdx.x;
    if (b < 8192) {
        size_t g = (size_t)b * 256 + threadIdx.x;   // one per 8 elems
        const f4* xp = (const f4*)x + g * 2;
        f4 a = xp[0], c = xp[1];
        u16x8 r;
        r[0] = f32_to_bf16_rne(a[0]); r[1] = f32_to_bf16_rne(a[1]);
        r[2] = f32_to_bf16_rne(a[2]); r[3] = f32_to_bf16_rne(a[3]);
        r[4] = f32_to_bf16_rne(c[0]); r[5] = f32_to_bf16_rne(c[1]);
        r[6] = f32_to_bf16_rne(c[2]); r[7] = f32_to_bf16_rne(c[3]);
        *((u16x8*)xb + g) = r;
    } else {
        size_t g = (size_t)(b - 8192) * 256 + threadIdx.x;
        int o  = (int)(g >> 9);
        int i0 = ((int)g & 511) << 3;
        int bs = (o >> 7) << 7;            // GEMM never reads i < 128-aligned block start
        if (i0 >= bs) {
            int off = o * IN_F - ((o * (o - 1)) >> 1);
            u16x8 r;
#pragma unroll
            for (int j = 0; j < 8; ++j) {
                int i = i0 + j;
                float v = (i >= o) ? wsrc[off + (i - o)] : 0.0f;
                r[j] = f32_to_bf16_rne(v);
            }
            *((u16x8*)wb + g) = r;
        }
    }
}

// ---- stage one 8-row x 128B unit via global_load_lds; dest linear, source pre-swizzled ----
// LDS row layout: [row][8 slots x 16B], byte(row,slot) = row*128 + (slot ^ (row&7))*16
__device__ __forceinline__ void stage16(const unsigned short* __restrict__ G,
                                        char* lds_dst, int gr0, int k0, int lane) {
    const int lrow  = lane >> 3;                 // 0..7
    const int gslot = (lane & 7) ^ lrow;         // pre-swizzled source slot
    const unsigned short* src = G + (size_t)(gr0 + lrow) * IN_F + k0 + gslot * 8;
    __builtin_amdgcn_global_load_lds(
        (const __attribute__((address_space(1))) void*)src,
        (__attribute__((address_space(3))) void*)lds_dst, 16, 0, 0);
}

__device__ __forceinline__ const bf16x8* lds_frag(const char* buf, int row, int slot) {
    return (const bf16x8*)(buf + row * 128 + ((slot ^ (row & 7)) * 16));
}

// ---- main GEMM: C[m][n] = sum_{k>=n_base} A[m][k]*W[n][k] + bias[n] ----
// 512 thr = 8 waves (2M x 2N x 2K). Wave tile 128x64, each wave does its k-half.
// 2 phases/K-tile, counted vmcnt(4), region-exact prefetch, LDS acc-reduction at end.
__global__ __launch_bounds__(512, 2) void tri_gemm_kernel(const unsigned short* __restrict__ A,
                                                          const unsigned short* __restrict__ W,
                                                          const float* __restrict__ bias,
                                                          float* __restrict__ C) {
    __shared__ __align__(16) char smem[2 * BUF_B];   // 96 KiB (dbuf; reused for reduction)

    const int u = blockIdx.x;
    const int tile_n = u >> 4;          // desc-K order -> greedy LPT, 66 steps/CU uniform
    const int tile_m = u & 15;
    const int m_base = tile_m * BM;
    const int n_base = tile_n * BN;
    const int nt = (IN_F - n_base) / BK;   // 64 - 2*tile_n, min 2

    const int tid  = threadIdx.x;
    const int wid  = tid >> 6;
    const int lane = tid & 63;
    const int wk = wid & 1;             // k-half owner
    const int wc = (wid >> 1) & 1;      // 64-col band
    const int wr = wid >> 2;            // 128-row band
    const int frow  = lane & 15;
    const int khalf = lane >> 4;
    const int slotb = wk * 4 + khalf;   // this wave's k slot (16B granule)

    char* cur = smem;
    char* nxt = smem + BUF_B;

    f32x4 acc[8][4];
#pragma unroll
    for (int i = 0; i < 8; ++i)
#pragma unroll
        for (int j = 0; j < 4; ++j) acc[i][j] = (f32x4){0.f, 0.f, 0.f, 0.f};

    // grp1 = {B0,B1,AQ0,AQ2} (4 issues/thread); grp2 = {AQ1,AQ3} (2 issues/thread)
#define ISSUE_GRP1(buf, kt)                                                        \
    do {                                                                           \
        stage16(W, (buf) + LDA_B + (wid * 16) * 128,     n_base + wid * 16,     (kt), lane); \
        stage16(W, (buf) + LDA_B + (wid * 16 + 8) * 128, n_base + wid * 16 + 8, (kt), lane); \
        stage16(A, (buf) + (wid * 8) * 128,       m_base + wid * 8,       (kt), lane); \
        stage16(A, (buf) + (128 + wid * 8) * 128, m_base + 128 + wid * 8, (kt), lane); \
    } while (0)
#define ISSUE_GRP2(buf, kt)                                                        \
    do {                                                                           \
        stage16(A, (buf) + (64 + wid * 8) * 128,  m_base + 64 + wid * 8,  (kt), lane); \
        stage16(A, (buf) + (192 + wid * 8) * 128, m_base + 192 + wid * 8, (kt), lane); \
    } while (0)

    // prologue: tile0 fully issued; tile1 grp1 in flight
    ISSUE_GRP1(cur, n_base);
    ISSUE_GRP2(cur, n_base);
    if (1 < nt) ISSUE_GRP1(nxt, n_base + BK);

    for (int t = 0; t < nt; ++t) {
        if (t + 1 < nt) { asm volatile("s_waitcnt vmcnt(4)" ::: "memory"); }
        else            { asm volatile("s_waitcnt vmcnt(0)" ::: "memory"); }
        __builtin_amdgcn_sched_barrier(0);
        __builtin_amdgcn_s_barrier();
        __builtin_amdgcn_sched_barrier(0);

        const char* bA = cur;
        const char* bB = cur + LDA_B;

        // ---- phase 1: A-rows [wr*128, wr*128+64) x all nj (16 MFMA) ----
        bf16x8 af[4], bfr[4];
#pragma unroll
        for (int mi = 0; mi < 4; ++mi)
            af[mi] = *lds_frag(bA, wr * 128 + mi * 16 + frow, slotb);
#pragma unroll
        for (int nj = 0; nj < 4; ++nj)
            bfr[nj] = *lds_frag(bB, wc * 64 + nj * 16 + frow, slotb);
        if (t + 1 < nt) ISSUE_GRP2(nxt, n_base + (t + 1) * BK);
        __builtin_amdgcn_s_barrier();
        asm volatile("s_waitcnt lgkmcnt(0)" ::: "memory");
        __builtin_amdgcn_sched_barrier(0);
        __builtin_amdgcn_s_setprio(1);
#pragma unroll
        for (int mi = 0; mi < 4; ++mi)
#pragma unroll
            for (int nj = 0; nj < 4; ++nj)
                acc[mi][nj] = __builtin_amdgcn_mfma_f32_16x16x32_bf16(af[mi], bfr[nj], acc[mi][nj], 0, 0, 0);
        __builtin_amdgcn_s_setprio(0);
        __builtin_amdgcn_s_barrier();

        // ---- phase 2: A-rows [wr*128+64, wr*128+128) x all nj (16 MFMA) ----
        bf16x8 ag[4];
#pragma unroll
        for (int mi = 0; mi < 4; ++mi)
            ag[mi] = *lds_frag(bA, wr * 128 + 64 + mi * 16 + frow, slotb);
        if (t + 2 < nt) ISSUE_GRP1(cur, n_base + (t + 2) * BK);   // B/AQ0/AQ2 freed by p1
        __builtin_amdgcn_s_barrier();
        asm volatile("s_waitcnt lgkmcnt(0)" ::: "memory");
        __builtin_amdgcn_sched_barrier(0);
        __builtin_amdgcn_s_setprio(1);
#pragma unroll
        for (int mi = 0; mi < 4; ++mi)
#pragma unroll
            for (int nj = 0; nj < 4; ++nj)
                acc[4 + mi][nj] = __builtin_amdgcn_mfma_f32_16x16x32_bf16(ag[mi], bfr[nj], acc[4 + mi][nj], 0, 0, 0);
        __builtin_amdgcn_s_setprio(0);
        // entry of next tile provides the closing barrier

        char* tmp = cur; cur = nxt; nxt = tmp;
    }

    // ---- k-half reduction: wk1 -> LDS -> wk0 adds (2 rounds x 64 frag-scalars) ----
    float* red = (float*)smem;
    const int pair = wid >> 1;                 // 0..3 = (wr,wc)
    const int rbase = pair * (64 * 66);        // 66-f32 stride: conflict-free
#pragma unroll
    for (int r = 0; r < 2; ++r) {
        __syncthreads();
        if (wk == 1) {
#pragma unroll
            for (int mi = 0; mi < 4; ++mi)
#pragma unroll
                for (int nj = 0; nj < 4; ++nj)
#pragma unroll
                    for (int q = 0; q < 4; ++q)
                        red[rbase + ((mi * 4 + nj) * 4 + q) * 66 + lane] = acc[r * 4 + mi][nj][q];
        }
        __syncthreads();
        if (wk == 0) {
#pragma unroll
            for (int mi = 0; mi < 4; ++mi)
#pragma unroll
                for (int nj = 0; nj < 4; ++nj)
#pragma unroll
                    for (int q = 0; q < 4; ++q)
                        acc[r * 4 + mi][nj][q] += red[rbase + ((mi * 4 + nj) * 4 + q) * 66 + lane];
        }
    }

    // ---- epilogue (wk0 waves): D layout col=lane&15, row=(lane>>4)*4+q ----
    if (wk == 0) {
        const int col0 = n_base + wc * 64;
        const int row0 = m_base + wr * 128;
#pragma unroll
        for (int nj = 0; nj < 4; ++nj) {
            const int col = col0 + nj * 16 + frow;
            const float bv = bias[col];
#pragma unroll
            for (int mi = 0; mi < 8; ++mi) {
                const int rb = row0 + mi * 16 + khalf * 4;
#pragma unroll
                for (int q = 0; q < 4; ++q) {
                    C[(size_t)(rb + q) * OUT_F + col] = acc[mi][nj][q] + bv;
                }
            }
        }
    }
#undef ISSUE_GRP1
#undef ISSUE_GRP2
}

extern "C" void kernel_launch(void* const* d_in, const int* in_sizes, int n_in,
                              void* d_out, int out_size, void* d_ws, size_t ws_size,
                              hipStream_t stream) {
    const float* x    = (const float*)d_in[0];
    const float* w    = (const float*)d_in[1];
    const float* bias = (const float*)d_in[2];
    float* out = (float*)d_out;

    unsigned short* xb = (unsigned short*)d_ws;                  // 32 MiB bf16 x
    unsigned short* wb = xb + (size_t)M_ROWS * IN_F;             // 32 MiB bf16 dense W

    prep_kernel<<<16384, 256, 0, stream>>>(x, w, xb, wb);
    tri_gemm_kernel<<<512, 512, 0, stream>>>(xb, wb, bias, out);
}

// Round 8
// 113.360 us; speedup vs baseline: 1.0932x; 1.0299x over previous
//
#include <hip/hip_runtime.h>
#include <stdint.h>

#define IN_F 4096
#define OUT_F 4096
#define M_ROWS 4096   // B*S
#define BM 256
#define BN 128
#define BK 64
#define LDA_B (BM * BK * 2)        // 32 KiB
#define LDB_B (BN * BK * 2)        // 16 KiB
#define BUF_B (LDA_B + LDB_B)      // 48 KiB

typedef __attribute__((ext_vector_type(8))) short bf16x8;
typedef __attribute__((ext_vector_type(4))) float f32x4;
typedef __attribute__((ext_vector_type(4))) float f4;
typedef __attribute__((ext_vector_type(8))) unsigned short u16x8;

__device__ __forceinline__ unsigned short f32_to_bf16_rne(float f) {
    uint32_t u = __float_as_uint(f);
    u += 0x7FFFu + ((u >> 16) & 1u);
    return (unsigned short)(u >> 16);
}

// ---- merged prepass: x fp32->bf16 (blocks [0,8192)), W expand (blocks [8192,16384)) ----
__global__ __launch_bounds__(256) void prep_kernel(const float* __restrict__ x,
                                                   const float* __restrict__ wsrc,
                                                   unsigned short* __restrict__ xb,
                                                   unsigned short* __restrict__ wb) {
    int b = blockIdx.x;
    if (b < 8192) {
        size_t g = (size_t)b * 256 + threadIdx.x;   // one per 8 elems
        const f4* xp = (const f4*)x + g * 2;
        f4 a = xp[0], c = xp[1];
        u16x8 r;
        r[0] = f32_to_bf16_rne(a[0]); r[1] = f32_to_bf16_rne(a[1]);
        r[2] = f32_to_bf16_rne(a[2]); r[3] = f32_to_bf16_rne(a[3]);
        r[4] = f32_to_bf16_rne(c[0]); r[5] = f32_to_bf16_rne(c[1]);
        r[6] = f32_to_bf16_rne(c[2]); r[7] = f32_to_bf16_rne(c[3]);
        *((u16x8*)xb + g) = r;
    } else {
        size_t g = (size_t)(b - 8192) * 256 + threadIdx.x;
        int o  = (int)(g >> 9);
        int i0 = ((int)g & 511) << 3;
        int bs = (o >> 7) << 7;            // GEMM never reads i < 128-aligned block start
        if (i0 >= bs) {
            int off = o * IN_F - ((o * (o - 1)) >> 1);
            u16x8 r;
#pragma unroll
            for (int j = 0; j < 8; ++j) {
                int i = i0 + j;
                float v = (i >= o) ? wsrc[off + (i - o)] : 0.0f;
                r[j] = f32_to_bf16_rne(v);
            }
            *((u16x8*)wb + g) = r;
        }
    }
}

// ---- stage one 8-row x 128B unit via global_load_lds; dest linear, source pre-swizzled ----
// LDS row layout: [row][8 slots x 16B], byte(row,slot) = row*128 + (slot ^ (row&7))*16
__device__ __forceinline__ void stage16(const unsigned short* __restrict__ G,
                                        char* lds_dst, int gr0, int k0, int lane) {
    const int lrow  = lane >> 3;                 // 0..7
    const int gslot = (lane & 7) ^ lrow;         // pre-swizzled source slot
    const unsigned short* src = G + (size_t)(gr0 + lrow) * IN_F + k0 + gslot * 8;
    __builtin_amdgcn_global_load_lds(
        (const __attribute__((address_space(1))) void*)src,
        (__attribute__((address_space(3))) void*)lds_dst, 16, 0, 0);
}

// one K64-tile: A 256x64 (4 chunks/wave) + B 128x64 (2 chunks/wave) = 6 issues/thread
__device__ __forceinline__ void stage_tile(const unsigned short* __restrict__ A,
                                           const unsigned short* __restrict__ W,
                                           char* buf, int m_base, int n_base, int k0,
                                           int wid, int lane) {
    char* bufA = buf;
    char* bufB = buf + LDA_B;
#pragma unroll
    for (int q = 0; q < 4; ++q) {                // A: 32 rows per wave
        const int r0 = q * 64 + wid * 8;
        stage16(A, bufA + r0 * 128, m_base + r0, k0, lane);
    }
#pragma unroll
    for (int q = 0; q < 2; ++q) {                // B: 16 rows per wave
        const int r0 = q * 64 + wid * 8;
        stage16(W, bufB + r0 * 128, n_base + r0, k0, lane);
    }
}

__device__ __forceinline__ const bf16x8* lds_frag(const char* buf, int row, int slot) {
    return (const bf16x8*)(buf + row * 128 + ((slot ^ (row & 7)) * 16));
}

// ---- main GEMM: C[m][n] = sum_{k>=n_base} A[m][k]*W[n][k] + bias[n] ----
// 512 thr = 8 waves (2M x 2N x 2K). Wave tile 128x64, each wave reads ONLY its k-half
// (12 ds_read_b128/wave/tile vs 16) -> LDS reads cut 25%. Schedule = R2's proven
// depth-3 circular, full-tile prefetch 2 tiles ahead, vmcnt(6), ONE barrier per tile.
__global__ __launch_bounds__(512, 2) void tri_gemm_kernel(const unsigned short* __restrict__ A,
                                                          const unsigned short* __restrict__ W,
                                                          const float* __restrict__ bias,
                                                          float* __restrict__ C) {
    __shared__ __align__(16) char smem[3 * BUF_B];   // 144 KiB (depth-3; reused for reduction)

    const int u = blockIdx.x;
    const int tile_n = u >> 4;          // desc-K order -> greedy LPT, 66 K-tiles/CU uniform
    const int tile_m = u & 15;
    const int m_base = tile_m * BM;
    const int n_base = tile_n * BN;
    const int nt = (IN_F - n_base) / BK;   // 64 - 2*tile_n, min 2

    const int tid  = threadIdx.x;
    const int wid  = tid >> 6;
    const int lane = tid & 63;
    const int wk = wid & 1;             // k-half owner
    const int wc = (wid >> 1) & 1;      // 64-col band
    const int wr = wid >> 2;            // 128-row band
    const int frow  = lane & 15;
    const int khalf = lane >> 4;
    const int slotb = wk * 4 + khalf;   // this wave's k 16B-slot within the K64 row

    char* b0 = smem;
    char* b1 = smem + BUF_B;
    char* b2 = smem + 2 * BUF_B;

    f32x4 acc[8][4];
#pragma unroll
    for (int i = 0; i < 8; ++i)
#pragma unroll
        for (int j = 0; j < 4; ++j) acc[i][j] = (f32x4){0.f, 0.f, 0.f, 0.f};

    // prologue: tiles 0,1 fully issued (6 loads each per thread) -> 2-tile lead
    stage_tile(A, W, b0, m_base, n_base, n_base,      wid, lane);
    stage_tile(A, W, b1, m_base, n_base, n_base + BK, wid, lane);

    for (int t = 0; t < nt; ++t) {
        if (t + 1 < nt) { asm volatile("s_waitcnt vmcnt(6)" ::: "memory"); }
        else            { asm volatile("s_waitcnt vmcnt(0)" ::: "memory"); }
        __builtin_amdgcn_sched_barrier(0);
        __builtin_amdgcn_s_barrier();     // tile t published; reads of t-1 retired by all waves
        __builtin_amdgcn_sched_barrier(0);

        if (t + 2 < nt)                   // prefetch t+2 into buffer freed by t-1
            stage_tile(A, W, b2, m_base, n_base, n_base + (t + 2) * BK, wid, lane);

        const char* bufA = b0;
        const char* bufB = b0 + LDA_B;
        bf16x8 af[8], bfv[4];
#pragma unroll
        for (int mi = 0; mi < 8; ++mi)
            af[mi] = *lds_frag(bufA, wr * 128 + mi * 16 + frow, slotb);
#pragma unroll
        for (int nj = 0; nj < 4; ++nj)
            bfv[nj] = *lds_frag(bufB, wc * 64 + nj * 16 + frow, slotb);

        __builtin_amdgcn_s_setprio(1);
#pragma unroll
        for (int mi = 0; mi < 8; ++mi)
#pragma unroll
            for (int nj = 0; nj < 4; ++nj)
                acc[mi][nj] = __builtin_amdgcn_mfma_f32_16x16x32_bf16(af[mi], bfv[nj], acc[mi][nj], 0, 0, 0);
        __builtin_amdgcn_s_setprio(0);

        asm volatile("s_waitcnt lgkmcnt(0)" ::: "memory");   // reads retired before next overwrite
        __builtin_amdgcn_sched_barrier(0);

        char* tmp = b0; b0 = b1; b1 = b2; b2 = tmp;   // rotate
    }

    // ---- k-half reduction: wk1 -> LDS -> wk0 adds (2 rounds x 64 frag-scalars) ----
    float* red = (float*)smem;
    const int pair = wid >> 1;                 // 0..3 = (wr,wc)
    const int rbase = pair * (64 * 66);        // 66-f32 stride: conflict-free
#pragma unroll
    for (int r = 0; r < 2; ++r) {
        __syncthreads();
        if (wk == 1) {
#pragma unroll
            for (int mi = 0; mi < 4; ++mi)
#pragma unroll
                for (int nj = 0; nj < 4; ++nj)
#pragma unroll
                    for (int q = 0; q < 4; ++q)
                        red[rbase + ((mi * 4 + nj) * 4 + q) * 66 + lane] = acc[r * 4 + mi][nj][q];
        }
        __syncthreads();
        if (wk == 0) {
#pragma unroll
            for (int mi = 0; mi < 4; ++mi)
#pragma unroll
                for (int nj = 0; nj < 4; ++nj)
#pragma unroll
                    for (int q = 0; q < 4; ++q)
                        acc[r * 4 + mi][nj][q] += red[rbase + ((mi * 4 + nj) * 4 + q) * 66 + lane];
        }
    }

    // ---- epilogue (wk0 waves): D layout col=lane&15, row=(lane>>4)*4+q ----
    if (wk == 0) {
        const int col0 = n_base + wc * 64;
        const int row0 = m_base + wr * 128;
#pragma unroll
        for (int nj = 0; nj < 4; ++nj) {
            const int col = col0 + nj * 16 + frow;
            const float bv = bias[col];
#pragma unroll
            for (int mi = 0; mi < 8; ++mi) {
                const int rb = row0 + mi * 16 + khalf * 4;
#pragma unroll
                for (int q = 0; q < 4; ++q) {
                    C[(size_t)(rb + q) * OUT_F + col] = acc[mi][nj][q] + bv;
                }
            }
        }
    }
}

extern "C" void kernel_launch(void* const* d_in, const int* in_sizes, int n_in,
                              void* d_out, int out_size, void* d_ws, size_t ws_size,
                              hipStream_t stream) {
    const float* x    = (const float*)d_in[0];
    const float* w    = (const float*)d_in[1];
    const float* bias = (const float*)d_in[2];
    float* out = (float*)d_out;

    unsigned short* xb = (unsigned short*)d_ws;                  // 32 MiB bf16 x
    unsigned short* wb = xb + (size_t)M_ROWS * IN_F;             // 32 MiB bf16 dense W

    prep_kernel<<<16384, 256, 0, stream>>>(x, w, xb, wb);
    tri_gemm_kernel<<<512, 512, 0, stream>>>(xb, wb, bias, out);
}